// Round 2
// baseline (12674.834 us; speedup 1.0000x reference)
//
#include <hip/hip_runtime.h>
#include <math.h>

#define D_OPT   128
#define N_SIM   2048
#define M_STEPS 64
#define HID     64

// One thread per (path, option) element; S,V live in registers across all 64
// SDE steps. __launch_bounds__(256, 4) caps VGPRs at 128 (grid = 4 blocks/CU
// = 4 waves/SIMD, so 8-wave occupancy is unreachable anyway) so that h1[64]
// and the 32-wide h2 tile ACTUALLY stay in registers — round 1's 52-VGPR
// allocation forced h1 rematerialization (~2.5x instruction bloat).
// Weights are read with wave-uniform addresses -> s_load + v_fmac v, s, v.
__global__ __launch_bounds__(256, 4) void nsde_kernel(
    const float* __restrict__ S0p, const float* __restrict__ Kp,
    const float* __restrict__ Tp,  const float* __restrict__ rfp,
    const float* __restrict__ V0p, const float* __restrict__ rhop,
    const float* __restrict__ Z1,  const float* __restrict__ Z2r,
    const float* __restrict__ W1,  const float* __restrict__ B1,
    const float* __restrict__ W2,  const float* __restrict__ B2,
    const float* __restrict__ W3,  const float* __restrict__ B3,
    float* __restrict__ out)
{
    const int e = blockIdx.x * 256 + threadIdx.x;     // [0, 262144)
    const int d = e & (D_OPT - 1);

    const float rf    = rfp[0];
    const float rho   = rhop[0];
    const float rho_c = sqrtf(1.0f - rho * rho);
    const float Td    = Tp[d];
    const float dt    = Td * (1.0f / (float)M_STEPS);
    const float sdt   = sqrtf(dt);

    float S = S0p[d];
    float V = V0p[0];

    #pragma unroll 1
    for (int s = 0; s < M_STEPS; ++s) {
        const size_t zoff = (size_t)s * (size_t)(N_SIM * D_OPT) + (size_t)e;
        const float z1  = Z1[zoff];
        const float z2r = Z2r[zoff];
        const float z2  = rho * z1 + rho_c * z2r;
        const float tj  = dt * (float)s;

        float N[4];
        #pragma unroll 1
        for (int k = 0; k < 4; ++k) {
            const float* __restrict__ w1  = W1 + k * 4 * HID;
            const float* __restrict__ bb1 = B1 + k * HID;
            const float* __restrict__ w2  = W2 + k * HID * HID;
            const float* __restrict__ bb2 = B2 + k * HID;
            const float* __restrict__ w3  = W3 + k * HID;

            // Layer 1: feat [S, V, rf, dt*j] @ W1[4,64] + b1, ReLU.
            // h1[64] stays resident in VGPRs for the whole k-iteration.
            float h1[HID];
            #pragma unroll
            for (int j = 0; j < HID; ++j) {
                float a = bb1[j];
                a = fmaf(S,  w1[0 * HID + j], a);
                a = fmaf(V,  w1[1 * HID + j], a);
                a = fmaf(rf, w1[2 * HID + j], a);
                a = fmaf(tj, w1[3 * HID + j], a);
                h1[j] = fmaxf(a, 0.0f);
            }

            // Layer 2 (64x64) in two 32-output tiles + fused layer-3 dot.
            float o = B3[k];
            #pragma unroll 1
            for (int jt = 0; jt < 2; ++jt) {
                float h2[32];
                #pragma unroll
                for (int jj = 0; jj < 32; ++jj) h2[jj] = bb2[jt * 32 + jj];
                #pragma unroll
                for (int i = 0; i < HID; ++i) {
                    const float hv = h1[i];
                    #pragma unroll
                    for (int jj = 0; jj < 32; ++jj)
                        h2[jj] = fmaf(hv, w2[i * HID + jt * 32 + jj], h2[jj]);
                }
                #pragma unroll
                for (int jj = 0; jj < 32; ++jj)
                    o = fmaf(fmaxf(h2[jj], 0.0f), w3[jt * 32 + jj], o);
            }

            // tanh(o) = 1 - 2/(e^{2o}+1); saturates correctly for |o| large
            const float ex = __expf(2.0f * o);
            N[k] = 1.0f - 2.0f / (ex + 1.0f);
        }

        S = S * (1.0f + N[0] * dt + N[1] * sdt * z1);
        V = V * (1.0f + N[2] * dt + N[3] * sdt * z2);
    }

    const float payoff  = fmaxf(S - Kp[d], 0.0f);
    const float contrib = __expf(-rf * Td) * payoff * (1.0f / (float)N_SIM);
    atomicAdd(&out[d], contrib);
}

extern "C" void kernel_launch(void* const* d_in, const int* in_sizes, int n_in,
                              void* d_out, int out_size, void* d_ws, size_t ws_size,
                              hipStream_t stream)
{
    const float* S0  = (const float*)d_in[0];
    const float* K   = (const float*)d_in[1];
    const float* T   = (const float*)d_in[2];
    const float* rf  = (const float*)d_in[3];
    const float* V0  = (const float*)d_in[4];
    const float* rho = (const float*)d_in[5];
    const float* Z1  = (const float*)d_in[6];
    const float* Z2r = (const float*)d_in[7];
    const float* W1  = (const float*)d_in[8];
    const float* B1  = (const float*)d_in[9];
    const float* W2  = (const float*)d_in[10];
    const float* B2  = (const float*)d_in[11];
    const float* W3  = (const float*)d_in[12];
    const float* B3  = (const float*)d_in[13];
    float* out = (float*)d_out;

    // d_out is poisoned 0xAA before every call; we accumulate with atomics.
    hipMemsetAsync(out, 0, (size_t)out_size * sizeof(float), stream);

    const int total  = N_SIM * D_OPT;          // 262144
    const int block  = 256;
    const int grid   = total / block;          // 1024
    nsde_kernel<<<grid, block, 0, stream>>>(S0, K, T, rf, V0, rho, Z1, Z2r,
                                            W1, B1, W2, B2, W3, B3, out);
}

// Round 3
// 6503.216 us; speedup vs baseline: 1.9490x; 1.9490x over previous
//
#include <hip/hip_runtime.h>
#include <math.h>

#define D_OPT   128
#define N_SIM   2048
#define M_STEPS 64
#define HID     64

// One thread per (path, option) element; S,V in registers across all 64 SDE
// steps. KEY STRUCTURE (round 3): the layer-2 GEMV is accumulator-resident —
// h2[64] accumulators live in VGPRs (cannot be rematerialized, unlike round
// 1/2's h1[64] which the allocator kept recomputing to hit a small VGPR
// budget). Each h1_i is a transient scalar: 4 FMA + ReLU, then immediately
// consumed by 64 FMAs into h2[]. i-loop stays rolled (unroll 2) so the step
// body is ~1 KB — no I$ thrash. Weights are wave-uniform -> s_load + 
// v_fmac v, s, v (1 SGPR per VALU op).
__global__ __launch_bounds__(256, 4) void nsde_kernel(
    const float* __restrict__ S0p, const float* __restrict__ Kp,
    const float* __restrict__ Tp,  const float* __restrict__ rfp,
    const float* __restrict__ V0p, const float* __restrict__ rhop,
    const float* __restrict__ Z1,  const float* __restrict__ Z2r,
    const float* __restrict__ W1,  const float* __restrict__ B1,
    const float* __restrict__ W2,  const float* __restrict__ B2,
    const float* __restrict__ W3,  const float* __restrict__ B3,
    float* __restrict__ out)
{
    const int e = blockIdx.x * 256 + threadIdx.x;     // [0, 262144)
    const int d = e & (D_OPT - 1);

    const float rf    = rfp[0];
    const float rho   = rhop[0];
    const float rho_c = sqrtf(1.0f - rho * rho);
    const float Td    = Tp[d];
    const float dt    = Td * (1.0f / (float)M_STEPS);
    const float sdt   = sqrtf(dt);

    float S = S0p[d];
    float V = V0p[0];

    #pragma unroll 1
    for (int s = 0; s < M_STEPS; ++s) {
        const size_t zoff = (size_t)s * (size_t)(N_SIM * D_OPT) + (size_t)e;
        const float z1  = Z1[zoff];
        const float z2r = Z2r[zoff];
        const float z2  = rho * z1 + rho_c * z2r;
        const float tj  = dt * (float)s;

        float N[4];
        #pragma unroll 1
        for (int k = 0; k < 4; ++k) {
            const float* __restrict__ w1  = W1 + k * 4 * HID;
            const float* __restrict__ bb1 = B1 + k * HID;
            const float* __restrict__ w2  = W2 + k * HID * HID;
            const float* __restrict__ bb2 = B2 + k * HID;
            const float* __restrict__ w3  = W3 + k * HID;

            // h2 accumulators: resident in VGPRs for the whole k-iteration.
            float h2[HID];
            #pragma unroll
            for (int j = 0; j < HID; ++j) h2[j] = bb2[j];

            // Fused layer 1 + layer 2: h1_i computed as a scalar and
            // immediately consumed — nothing for the allocator to remat.
            #pragma unroll 2
            for (int i = 0; i < HID; ++i) {
                float a = bb1[i];
                a = fmaf(S,  w1[0 * HID + i], a);
                a = fmaf(V,  w1[1 * HID + i], a);
                a = fmaf(rf, w1[2 * HID + i], a);
                a = fmaf(tj, w1[3 * HID + i], a);
                const float hv = fmaxf(a, 0.0f);
                const float* __restrict__ wr = w2 + i * HID;
                #pragma unroll
                for (int j = 0; j < HID; ++j)
                    h2[j] = fmaf(hv, wr[j], h2[j]);
            }

            // Layer 3 dot with ReLU on h2
            float o = B3[k];
            #pragma unroll
            for (int j = 0; j < HID; ++j)
                o = fmaf(fmaxf(h2[j], 0.0f), w3[j], o);

            // tanh(o) = 1 - 2/(e^{2o}+1); saturates correctly for |o| large
            const float ex = __expf(2.0f * o);
            N[k] = 1.0f - 2.0f / (ex + 1.0f);
        }

        S = S * (1.0f + N[0] * dt + N[1] * sdt * z1);
        V = V * (1.0f + N[2] * dt + N[3] * sdt * z2);
    }

    const float payoff  = fmaxf(S - Kp[d], 0.0f);
    const float contrib = __expf(-rf * Td) * payoff * (1.0f / (float)N_SIM);
    atomicAdd(&out[d], contrib);
}

extern "C" void kernel_launch(void* const* d_in, const int* in_sizes, int n_in,
                              void* d_out, int out_size, void* d_ws, size_t ws_size,
                              hipStream_t stream)
{
    const float* S0  = (const float*)d_in[0];
    const float* K   = (const float*)d_in[1];
    const float* T   = (const float*)d_in[2];
    const float* rf  = (const float*)d_in[3];
    const float* V0  = (const float*)d_in[4];
    const float* rho = (const float*)d_in[5];
    const float* Z1  = (const float*)d_in[6];
    const float* Z2r = (const float*)d_in[7];
    const float* W1  = (const float*)d_in[8];
    const float* B1  = (const float*)d_in[9];
    const float* W2  = (const float*)d_in[10];
    const float* B2  = (const float*)d_in[11];
    const float* W3  = (const float*)d_in[12];
    const float* B3  = (const float*)d_in[13];
    float* out = (float*)d_out;

    // d_out is poisoned 0xAA before every call; we accumulate with atomics.
    hipMemsetAsync(out, 0, (size_t)out_size * sizeof(float), stream);

    const int total  = N_SIM * D_OPT;          // 262144
    const int block  = 256;
    const int grid   = total / block;          // 1024
    nsde_kernel<<<grid, block, 0, stream>>>(S0, K, T, rf, V0, rho, Z1, Z2r,
                                            W1, B1, W2, B2, W3, B3, out);
}

// Round 4
// 2032.136 us; speedup vs baseline: 6.2372x; 3.2002x over previous
//
#include <hip/hip_runtime.h>
#include <math.h>

#define D_OPT   128
#define N_SIM   2048
#define M_STEPS 64
#define HID     64

// Round 4: MFMA rewrite.
// Layer-2 ([E x 64] @ [64 x 64], 93% of MACs) runs on matrix cores as
// mfma_f32_16x16x32_f16. Each wave owns 16 elements (M=16).
//   A-frag (h1):  lane holds A[m=lane&15][k=(lane>>4)*8+j] — layer-1 is VALU,
//                 computed directly into this layout (lane needs only element
//                 lane&15's state SA,VA).
//   B-frag (W2):  lane holds B[k=(lane>>4)*8+j][n=(lane&15)+16t], staged once
//                 into LDS as fp16 at block start.
//   C/D:          lane holds rows m=4*(lane>>4)+r, col n=(lane&15)+16t —
//                 S,V,dt,z state is kept per-lane for rows 4q..4q+3
//                 (replicated 16x across the q-group; redundant VALU is cheap).
// Layer-3: in-register relu-dot over the lane's 4 n's, then 4-step
// __shfl_xor butterfly over the 16-lane group -> every lane has o for its 4
// rows. tanh + SDE factor accumulation per net. One 128B LDS bounce per step
// re-distributes updated S,V into A-layout (same-wave ds ordering, no barrier).
typedef _Float16 f16x8 __attribute__((ext_vector_type(8)));
typedef float    f32x4 __attribute__((ext_vector_type(4)));

__global__ __launch_bounds__(256, 4) void nsde_kernel(
    const float* __restrict__ S0p, const float* __restrict__ Kp,
    const float* __restrict__ Tp,  const float* __restrict__ rfp,
    const float* __restrict__ V0p, const float* __restrict__ rhop,
    const float* __restrict__ Z1,  const float* __restrict__ Z2r,
    const float* __restrict__ W1,  const float* __restrict__ B1,
    const float* __restrict__ W2,  const float* __restrict__ B2,
    const float* __restrict__ W3,  const float* __restrict__ B3,
    float* __restrict__ out)
{
    __shared__ f16x8 w2frag[32 * 64];   // [net*8+t*2+kt][lane], 32 KB
    __shared__ f32x4 w1p[4 * 64];       // [net][j] = {w_S, w_V, w_tj, rf*w_rf+b1}, 4 KB
    __shared__ f32x4 b2lane[4 * 16];    // [net][m] components t=0..3, 1 KB
    __shared__ f32x4 w3lane[4 * 16];    // [net][m] components t=0..3, 1 KB
    __shared__ float svb[4][16][2];     // [wave][m]{S,V}, 512 B

    const int tid = threadIdx.x;
    const float rf = rfp[0];

    // ---- stage weights into LDS ----
    {
        const int net = tid >> 6, j = tid & 63;
        const float* w1g = W1 + net * 256;
        f32x4 w;
        w[0] = w1g[0 * 64 + j];
        w[1] = w1g[1 * 64 + j];
        w[2] = w1g[3 * 64 + j];                               // tj coeff
        w[3] = fmaf(rf, w1g[2 * 64 + j], B1[net * 64 + j]);   // rf*w + b1
        w1p[tid] = w;
        if (tid < 64) {
            const int n2 = tid >> 4, m = tid & 15;
            f32x4 b, u;
            #pragma unroll
            for (int t = 0; t < 4; ++t) {
                b[t] = B2[n2 * 64 + 16 * t + m];
                u[t] = W3[n2 * 64 + 16 * t + m];
            }
            b2lane[tid] = b;
            w3lane[tid] = u;
        }
    }
    #pragma unroll
    for (int f = 0; f < 8; ++f) {
        const int id    = f * 256 + tid;          // 0..2047 lane-frags
        const int lane_ = id & 63;
        const int fi    = id >> 6;                // 0..31
        const int net   = fi >> 3, t = (fi >> 1) & 3, kt = fi & 1;
        const int n     = 16 * t + (lane_ & 15);
        const int k0    = kt * 32 + (lane_ >> 4) * 8;
        const float* w2g = W2 + net * 4096;
        f16x8 h;
        #pragma unroll
        for (int jj = 0; jj < 8; ++jj)
            h[jj] = (_Float16)w2g[(k0 + jj) * 64 + n];
        w2frag[id] = h;
    }
    __syncthreads();

    // ---- per-wave setup ----
    const int wave = tid >> 6;
    const int lane = tid & 63;
    const int q    = lane >> 4;
    const int mA   = lane & 15;                         // A-side element (row)
    const int ebase = blockIdx.x * 64 + wave * 16;
    const int er0   = ebase + 4 * q;                    // first replicated row

    float S_r[4], V_r[4], dt_r[4], sdt_r[4];
    #pragma unroll
    for (int r = 0; r < 4; ++r) {
        const int d = (er0 + r) & (D_OPT - 1);
        dt_r[r]  = Tp[d] * (1.0f / (float)M_STEPS);
        sdt_r[r] = sqrtf(dt_r[r]);
        S_r[r]   = S0p[d];
        V_r[r]   = V0p[0];
    }
    const int dA = (ebase + mA) & (D_OPT - 1);
    const float dtA = Tp[dA] * (1.0f / (float)M_STEPS);
    float SA = S0p[dA];
    float VA = V0p[0];

    const float rho   = rhop[0];
    const float rho_c = sqrtf(1.0f - rho * rho);
    const float b3v0 = B3[0], b3v1 = B3[1], b3v2 = B3[2], b3v3 = B3[3];

    const size_t estep = (size_t)N_SIM * D_OPT;

    #pragma unroll 1
    for (int s = 0; s < M_STEPS; ++s) {
        const size_t zoff = (size_t)s * estep + (size_t)er0;
        const f32x4 z1v  = *(const f32x4*)(Z1 + zoff);
        const f32x4 z2rv = *(const f32x4*)(Z2r + zoff);
        float z2_r[4];
        #pragma unroll
        for (int r = 0; r < 4; ++r)
            z2_r[r] = fmaf(rho, z1v[r], rho_c * z2rv[r]);
        const float tjA = dtA * (float)s;

        float factS[4] = {0.f, 0.f, 0.f, 0.f};
        float factV[4] = {0.f, 0.f, 0.f, 0.f};

        #pragma unroll 1
        for (int net = 0; net < 4; ++net) {
            // ---- layer 1 (VALU) directly into A-fragments ----
            const f32x4* w1pn = &w1p[net * 64];
            f16x8 a0, a1;
            const int jb = q * 8;
            #pragma unroll
            for (int jj = 0; jj < 8; ++jj) {
                f32x4 w = w1pn[jb + jj];
                float a = w[3];
                a = fmaf(SA,  w[0], a);
                a = fmaf(VA,  w[1], a);
                a = fmaf(tjA, w[2], a);
                a0[jj] = (_Float16)fmaxf(a, 0.0f);
                f32x4 v = w1pn[32 + jb + jj];
                float b = v[3];
                b = fmaf(SA,  v[0], b);
                b = fmaf(VA,  v[1], b);
                b = fmaf(tjA, v[2], b);
                a1[jj] = (_Float16)fmaxf(b, 0.0f);
            }

            // ---- layer 2 (MFMA), K=64 as 2 chained k-tiles, 4 n-tiles ----
            const f32x4 b2v = b2lane[net * 16 + mA];
            const f32x4 w3v = w3lane[net * 16 + mA];
            float op[4] = {0.f, 0.f, 0.f, 0.f};
            #pragma unroll
            for (int t = 0; t < 4; ++t) {
                f32x4 acc;
                acc[0] = b2v[t]; acc[1] = b2v[t]; acc[2] = b2v[t]; acc[3] = b2v[t];
                acc = __builtin_amdgcn_mfma_f32_16x16x32_f16(
                          a0, w2frag[(net * 8 + t * 2 + 0) * 64 + lane], acc, 0, 0, 0);
                acc = __builtin_amdgcn_mfma_f32_16x16x32_f16(
                          a1, w2frag[(net * 8 + t * 2 + 1) * 64 + lane], acc, 0, 0, 0);
                // ---- layer 3 partial: relu + dot with w3 over this n ----
                #pragma unroll
                for (int r = 0; r < 4; ++r)
                    op[r] = fmaf(fmaxf(acc[r], 0.0f), w3v[t], op[r]);
            }

            // ---- butterfly sum over the 16-lane group (cols 0..15) ----
            #pragma unroll
            for (int msk = 1; msk < 16; msk <<= 1) {
                #pragma unroll
                for (int r = 0; r < 4; ++r)
                    op[r] += __shfl_xor(op[r], msk, 64);
            }

            const float b3v = (net == 0) ? b3v0 : (net == 1) ? b3v1
                            : (net == 2) ? b3v2 : b3v3;
            #pragma unroll
            for (int r = 0; r < 4; ++r) {
                const float o  = op[r] + b3v;
                const float ex = __expf(2.0f * o);
                const float Nv = 1.0f - 2.0f / (ex + 1.0f);
                if      (net == 0) factS[r] = Nv * dt_r[r];
                else if (net == 1) factS[r] = fmaf(Nv * sdt_r[r], z1v[r], factS[r]);
                else if (net == 2) factV[r] = Nv * dt_r[r];
                else               factV[r] = fmaf(Nv * sdt_r[r], z2_r[r], factV[r]);
            }
        }

        // ---- SDE update on replicated rows ----
        #pragma unroll
        for (int r = 0; r < 4; ++r) {
            S_r[r] *= (1.0f + factS[r]);
            V_r[r] *= (1.0f + factV[r]);
        }

        // ---- bounce S,V to A-layout (same-wave LDS, no barrier needed) ----
        if (mA == 4 * q) {          // lanes 0,20,40,60 write their 4 rows
            #pragma unroll
            for (int r = 0; r < 4; ++r) {
                svb[wave][4 * q + r][0] = S_r[r];
                svb[wave][4 * q + r][1] = V_r[r];
            }
        }
        SA = svb[wave][mA][0];
        VA = svb[wave][mA][1];
    }

    // ---- payoff: one lane per element (q==0 lanes hold final SA for mA) ----
    if (q == 0) {
        const float Td      = dtA * (float)M_STEPS;
        const float payoff  = fmaxf(SA - Kp[dA], 0.0f);
        const float contrib = __expf(-rf * Td) * payoff * (1.0f / (float)N_SIM);
        atomicAdd(&out[dA], contrib);
    }
}

extern "C" void kernel_launch(void* const* d_in, const int* in_sizes, int n_in,
                              void* d_out, int out_size, void* d_ws, size_t ws_size,
                              hipStream_t stream)
{
    const float* S0  = (const float*)d_in[0];
    const float* K   = (const float*)d_in[1];
    const float* T   = (const float*)d_in[2];
    const float* rf  = (const float*)d_in[3];
    const float* V0  = (const float*)d_in[4];
    const float* rho = (const float*)d_in[5];
    const float* Z1  = (const float*)d_in[6];
    const float* Z2r = (const float*)d_in[7];
    const float* W1  = (const float*)d_in[8];
    const float* B1  = (const float*)d_in[9];
    const float* W2  = (const float*)d_in[10];
    const float* B2  = (const float*)d_in[11];
    const float* W3  = (const float*)d_in[12];
    const float* B3  = (const float*)d_in[13];
    float* out = (float*)d_out;

    hipMemsetAsync(out, 0, (size_t)out_size * sizeof(float), stream);

    const int total = N_SIM * D_OPT;              // 262144 elements
    const int grid  = total / 64;                 // 64 elements per block
    nsde_kernel<<<grid, 256, 0, stream>>>(S0, K, T, rf, V0, rho, Z1, Z2r,
                                          W1, B1, W2, B2, W3, B3, out);
}

// Round 6
// 1292.947 us; speedup vs baseline: 9.8031x; 1.5717x over previous
//
#include <hip/hip_runtime.h>
#include <math.h>

#define D_OPT   128
#define N_SIM   2048
#define M_STEPS 64
#define HID     64

// Round 6: net-specialized waves (R5 architecture) + payoff-guard fix.
// R5's absmax 88.5 was exactly 3x max|P_ref| (29.5): the payoff used
// `if (wave==0)` which kept all 4 q-replicas -> each element added 4x.
// Fix: `if (wave==0 && q==0)`. Everything else verified by inspection:
//   - Wave w owns net w for all 64 block elements; W2 B-frags (32 VGPRs),
//     packed-fp16 W1 coeffs (32 VGPRs), b2/w3 (8 VGPRs) register-resident.
//   - Layer-1 on v_pk_fma_f16 producing A-fragments directly.
//   - 16-lane column reduction via DPP row_ror butterfly (no DS/addr VALU).
//   - tanh once per (element, net) via lane bijection; results exchanged
//     through double-buffered nv_lds; ONE __syncthreads per step (write(s+2)
//     ordered after read(s) by the barrier chain).
//   - S,V per-lane for 4 elements, replicated across q-groups (identical
//     updates from shared N values).

typedef _Float16 f16x8 __attribute__((ext_vector_type(8)));
typedef _Float16 f16x2 __attribute__((ext_vector_type(2)));
typedef float    f32x4 __attribute__((ext_vector_type(4)));
typedef unsigned int u32;
typedef u32 u32x4 __attribute__((ext_vector_type(4)));

#if __has_builtin(__builtin_elementwise_fma)
#define PK_FMA(a,b,c) __builtin_elementwise_fma((a),(b),(c))
#else
#define PK_FMA(a,b,c) ((a)*(b)+(c))
#endif

__device__ __forceinline__ f16x2 pk_relu(f16x2 v) {
    f16x2 z = { (_Float16)0.0f, (_Float16)0.0f };
#if __has_builtin(__builtin_elementwise_max)
    return __builtin_elementwise_max(v, z);
#else
    f16x2 r;
    r.x = v.x > (_Float16)0 ? v.x : (_Float16)0;
    r.y = v.y > (_Float16)0 ? v.y : (_Float16)0;
    return r;
#endif
}

// ROW_ROR:n within each 16-lane row: 0x120|n. Rotation butterfly (8,4,2,1)
// leaves the full 16-lane sum replicated in every lane of the row.
template<int CTRL>
__device__ __forceinline__ float ror_add(float x) {
    int i = __builtin_bit_cast(int, x);
    int r = __builtin_amdgcn_update_dpp(i, i, CTRL, 0xf, 0xf, false);
    return x + __builtin_bit_cast(float, r);
}

union AF { f16x2 p[4]; f16x8 v; };

__global__ __launch_bounds__(256, 3) void nsde_kernel(
    const float* __restrict__ S0p, const float* __restrict__ Kp,
    const float* __restrict__ Tp,  const float* __restrict__ rfp,
    const float* __restrict__ V0p, const float* __restrict__ rhop,
    const float* __restrict__ Z1,  const float* __restrict__ Z2r,
    const float* __restrict__ W1,  const float* __restrict__ B1,
    const float* __restrict__ W2,  const float* __restrict__ B2,
    const float* __restrict__ W3,  const float* __restrict__ B3,
    float* __restrict__ out)
{
    __shared__ f16x8 w2frag[32 * 64];   // [net*8 + t*2 + kt][lane], 32 KB
    __shared__ u32x4 w1h[128];          // [((net*2+kt)*4+jj)*4+q] packed f16x2 coeffs, 2 KB
    __shared__ f32x4 b2lane[4 * 16];    // [net*16+m] components t=0..3, 1 KB
    __shared__ f32x4 w3lane[4 * 16];    // [net*16+m] components t=0..3, 1 KB
    __shared__ f32x4 nv_lds[2][64];     // [buf][element] = {N1,N2,N3,N4}, 2 KB

    const int tid  = threadIdx.x;
    const int wave = tid >> 6;
    const int lane = tid & 63;
    const int q    = lane >> 4;
    const int mA   = lane & 15;
    const float rf = rfp[0];

    // ---------------- stage weights into LDS ----------------
    if (tid < 128) {
        // slot = ((net*2+kt)*4+jj)*4+q ; pair covers hidden units u0,u0+1
        const int net = tid >> 5, kt = (tid >> 4) & 1, jj = (tid >> 2) & 3, qq = tid & 3;
        const int u0 = kt * 32 + qq * 8 + 2 * jj, u1 = u0 + 1;
        const float* w1g = W1 + net * 256;
        const float* b1g = B1 + net * 64;
        f16x2 wS = { (_Float16)w1g[0 * 64 + u0], (_Float16)w1g[0 * 64 + u1] };
        f16x2 wV = { (_Float16)w1g[1 * 64 + u0], (_Float16)w1g[1 * 64 + u1] };
        f16x2 wt = { (_Float16)w1g[3 * 64 + u0], (_Float16)w1g[3 * 64 + u1] };
        f16x2 cc = { (_Float16)fmaf(rf, w1g[2 * 64 + u0], b1g[u0]),
                     (_Float16)fmaf(rf, w1g[2 * 64 + u1], b1g[u1]) };
        u32x4 slot;
        slot[0] = __builtin_bit_cast(u32, wS);
        slot[1] = __builtin_bit_cast(u32, wV);
        slot[2] = __builtin_bit_cast(u32, wt);
        slot[3] = __builtin_bit_cast(u32, cc);
        w1h[tid] = slot;
    }
    if (tid < 64) {
        const int n2 = tid >> 4, m = tid & 15;
        f32x4 b, u;
        #pragma unroll
        for (int t = 0; t < 4; ++t) {
            b[t] = B2[n2 * 64 + 16 * t + m];
            u[t] = W3[n2 * 64 + 16 * t + m];
        }
        b2lane[tid] = b;
        w3lane[tid] = u;
    }
    #pragma unroll
    for (int f = 0; f < 8; ++f) {
        const int id    = f * 256 + tid;          // 2048 lane-frags
        const int lane_ = id & 63;
        const int fi    = id >> 6;                // 0..31
        const int net   = fi >> 3, t = (fi >> 1) & 3, kt = fi & 1;
        const int n     = 16 * t + (lane_ & 15);
        const int k0    = kt * 32 + (lane_ >> 4) * 8;
        const float* w2g = W2 + net * 4096;
        f16x8 h;
        #pragma unroll
        for (int jjj = 0; jjj < 8; ++jjj)
            h[jjj] = (_Float16)w2g[(k0 + jjj) * 64 + n];
        w2frag[id] = h;
    }
    __syncthreads();

    // ---------------- hoist wave-resident weights into registers ----------------
    f16x8 Bf[4][2];                      // W2 B-frags for net = wave (32 VGPRs)
    #pragma unroll
    for (int t = 0; t < 4; ++t)
        #pragma unroll
        for (int kt = 0; kt < 2; ++kt)
            Bf[t][kt] = w2frag[(wave * 8 + t * 2 + kt) * 64 + lane];

    f16x2 cw[2][4][4];                   // packed W1 coeffs (32 VGPRs)
    #pragma unroll
    for (int kt = 0; kt < 2; ++kt)
        #pragma unroll
        for (int jj = 0; jj < 4; ++jj) {
            u32x4 v = w1h[((wave * 2 + kt) * 4 + jj) * 4 + q];
            cw[kt][jj][0] = __builtin_bit_cast(f16x2, v[0]);
            cw[kt][jj][1] = __builtin_bit_cast(f16x2, v[1]);
            cw[kt][jj][2] = __builtin_bit_cast(f16x2, v[2]);
            cw[kt][jj][3] = __builtin_bit_cast(f16x2, v[3]);
        }
    const f32x4 b2v = b2lane[wave * 16 + mA];
    const f32x4 w3v = w3lane[wave * 16 + mA];
    const float b3w = B3[wave];

    // ---------------- per-element state (4 elements per lane) ----------------
    const int ebase = blockIdx.x * 64;
    float S[4], V[4], dt[4], sdt[4];
    #pragma unroll
    for (int mt = 0; mt < 4; ++mt) {
        const int d = (ebase + mt * 16 + mA) & (D_OPT - 1);
        dt[mt]  = Tp[d] * (1.0f / (float)M_STEPS);
        sdt[mt] = sqrtf(dt[mt]);
        S[mt]   = S0p[d];
        V[mt]   = V0p[0];
    }
    const float rho   = rhop[0];
    const float rho_c = sqrtf(1.0f - rho * rho);
    const size_t estep = (size_t)N_SIM * D_OPT;

    #pragma unroll 1
    for (int s = 0; s < M_STEPS; ++s) {
        // z loads for this lane's 4 elements (issued early to hide latency)
        const size_t zbase = (size_t)s * estep + (size_t)ebase;
        float z1r[4], z2rr[4];
        #pragma unroll
        for (int mt = 0; mt < 4; ++mt) {
            z1r[mt]  = Z1[zbase + mt * 16 + mA];
            z2rr[mt] = Z2r[zbase + mt * 16 + mA];
        }

        #pragma unroll
        for (int mt = 0; mt < 4; ++mt) {
            // packed feat for this element
            const _Float16 sh = (_Float16)S[mt];
            const _Float16 vh = (_Float16)V[mt];
            const _Float16 th = (_Float16)(dt[mt] * (float)s);
            const f16x2 S2 = { sh, sh };
            const f16x2 V2 = { vh, vh };
            const f16x2 T2 = { th, th };

            // layer 1 (packed fp16) straight into A-fragments
            AF a0, a1;
            #pragma unroll
            for (int jj = 0; jj < 4; ++jj) {
                f16x2 h0 = PK_FMA(S2, cw[0][jj][0],
                            PK_FMA(V2, cw[0][jj][1],
                             PK_FMA(T2, cw[0][jj][2], cw[0][jj][3])));
                a0.p[jj] = pk_relu(h0);
                f16x2 h1 = PK_FMA(S2, cw[1][jj][0],
                            PK_FMA(V2, cw[1][jj][1],
                             PK_FMA(T2, cw[1][jj][2], cw[1][jj][3])));
                a1.p[jj] = pk_relu(h1);
            }

            // layer 2 (MFMA) + fused layer-3 partial over this lane's cols
            float op[4] = {0.f, 0.f, 0.f, 0.f};
            #pragma unroll
            for (int t = 0; t < 4; ++t) {
                f32x4 acc;
                acc[0] = b2v[t]; acc[1] = b2v[t]; acc[2] = b2v[t]; acc[3] = b2v[t];
                acc = __builtin_amdgcn_mfma_f32_16x16x32_f16(a0.v, Bf[t][0], acc, 0, 0, 0);
                acc = __builtin_amdgcn_mfma_f32_16x16x32_f16(a1.v, Bf[t][1], acc, 0, 0, 0);
                #pragma unroll
                for (int r = 0; r < 4; ++r)
                    op[r] = fmaf(fmaxf(acc[r], 0.0f), w3v[t], op[r]);
            }

            // DPP rotation butterfly: full 16-lane sum, replicated
            #pragma unroll
            for (int r = 0; r < 4; ++r) {
                op[r] = ror_add<0x128>(op[r]);  // ror 8
                op[r] = ror_add<0x124>(op[r]);  // ror 4
                op[r] = ror_add<0x122>(op[r]);  // ror 2
                op[r] = ror_add<0x121>(op[r]);  // ror 1
            }

            // bijection: lane (q, mA) with mA>>2 == mt handles element
            // e = mt*16 + 4q + (mA&3): tanh once per (element, net)
            if ((mA >> 2) == mt) {
                const int r = mA & 3;
                float o = (r == 0) ? op[0] : (r == 1) ? op[1]
                        : (r == 2) ? op[2] : op[3];
                o += b3w;
                const float ex = __expf(2.0f * o);
                const float Nv = 1.0f - 2.0f / (ex + 1.0f);
                const int e_w  = mt * 16 + 4 * q + r;
                ((float*)&nv_lds[s & 1][e_w])[wave] = Nv;
            }
        }

        __syncthreads();

        // SDE update: read all 4 nets' N for this lane's 4 elements
        #pragma unroll
        for (int mt = 0; mt < 4; ++mt) {
            const f32x4 Nv4 = nv_lds[s & 1][mt * 16 + mA];
            const float z2 = fmaf(rho, z1r[mt], rho_c * z2rr[mt]);
            const float fS = fmaf(Nv4[1] * sdt[mt], z1r[mt], Nv4[0] * dt[mt]);
            const float fV = fmaf(Nv4[3] * sdt[mt], z2,       Nv4[2] * dt[mt]);
            S[mt] = fmaf(S[mt], fS, S[mt]);
            V[mt] = fmaf(V[mt], fV, V[mt]);
        }
    }

    // ---- payoff: wave 0, q==0 only — ONE lane per element (R5 bug: all 4
    // q-replicas added -> P was exactly 4x reference; absmax 88.5 = 3x29.5) ----
    if (wave == 0 && q == 0) {
        #pragma unroll
        for (int mt = 0; mt < 4; ++mt) {
            const int d = (ebase + mt * 16 + mA) & (D_OPT - 1);
            const float Td  = dt[mt] * (float)M_STEPS;
            const float pay = fmaxf(S[mt] - Kp[d], 0.0f);
            atomicAdd(&out[d], __expf(-rf * Td) * pay * (1.0f / (float)N_SIM));
        }
    }
}

extern "C" void kernel_launch(void* const* d_in, const int* in_sizes, int n_in,
                              void* d_out, int out_size, void* d_ws, size_t ws_size,
                              hipStream_t stream)
{
    const float* S0  = (const float*)d_in[0];
    const float* K   = (const float*)d_in[1];
    const float* T   = (const float*)d_in[2];
    const float* rf  = (const float*)d_in[3];
    const float* V0  = (const float*)d_in[4];
    const float* rho = (const float*)d_in[5];
    const float* Z1  = (const float*)d_in[6];
    const float* Z2r = (const float*)d_in[7];
    const float* W1  = (const float*)d_in[8];
    const float* B1  = (const float*)d_in[9];
    const float* W2  = (const float*)d_in[10];
    const float* B2  = (const float*)d_in[11];
    const float* W3  = (const float*)d_in[12];
    const float* B3  = (const float*)d_in[13];
    float* out = (float*)d_out;

    hipMemsetAsync(out, 0, (size_t)out_size * sizeof(float), stream);

    const int total = N_SIM * D_OPT;              // 262144 elements
    const int grid  = total / 64;                 // 64 elements per block
    nsde_kernel<<<grid, 256, 0, stream>>>(S0, K, T, rf, V0, rho, Z1, Z2r,
                                          W1, B1, W2, B2, W3, B3, out);
}

// Round 7
// 1079.373 us; speedup vs baseline: 11.7428x; 1.1979x over previous
//
#include <hip/hip_runtime.h>
#include <math.h>

#define D_OPT   128
#define N_SIM   2048
#define M_STEPS 64
#define HID     64

// Round 7: R6 architecture (net-specialized waves, register/AGPR-resident
// weights, MFMA layer-2) with issued-instruction cuts (we are VALU-issue
// bound at 97%):
//  - SDE update 16x-dedup: lane updates ONLY element e==lane (mt=q slot);
//    S,V exchanged via wave-PRIVATE LDS (svx) -> no barrier, z loads 8->2.
//  - MFMA C operand = hoisted bias splats cinit[t] -> zero per-tile movs.
//  - DPP reduce via mov_dpp (combiner-friendly -> v_add_f32_dpp).
//  - tanh once per lane in update phase (nv_lds carries pre-tanh o).
//  - payoff: wave 0, lane==element — replication-safe by construction.

typedef _Float16 f16x8 __attribute__((ext_vector_type(8)));
typedef _Float16 f16x2 __attribute__((ext_vector_type(2)));
typedef float    f32x4 __attribute__((ext_vector_type(4)));
typedef unsigned int u32;
typedef u32 u32x4 __attribute__((ext_vector_type(4)));

#if __has_builtin(__builtin_elementwise_fma)
#define PK_FMA(a,b,c) __builtin_elementwise_fma((a),(b),(c))
#else
#define PK_FMA(a,b,c) ((a)*(b)+(c))
#endif

__device__ __forceinline__ f16x2 pk_relu(f16x2 v) {
    f16x2 z = { (_Float16)0.0f, (_Float16)0.0f };
#if __has_builtin(__builtin_elementwise_max)
    return __builtin_elementwise_max(v, z);
#else
    f16x2 r;
    r[0] = v[0] > (_Float16)0 ? v[0] : (_Float16)0;
    r[1] = v[1] > (_Float16)0 ? v[1] : (_Float16)0;
    return r;
#endif
}

__device__ __forceinline__ f16x2 pk2(float x) {
#if __has_builtin(__builtin_amdgcn_cvt_pkrtz)
    return __builtin_bit_cast(f16x2, __builtin_amdgcn_cvt_pkrtz(x, x));
#else
    f16x2 r; r[0] = (_Float16)x; r[1] = (_Float16)x; return r;
#endif
}

// x + row_ror(x): with full row/bank masks the DPP-combine pass can fold
// mov_dpp + add into a single v_add_f32_dpp.
template<int CTRL>
__device__ __forceinline__ float ror_add(float x) {
    int i = __builtin_bit_cast(int, x);
#if __has_builtin(__builtin_amdgcn_mov_dpp)
    int r = __builtin_amdgcn_mov_dpp(i, CTRL, 0xf, 0xf, true);
#else
    int r = __builtin_amdgcn_update_dpp(i, i, CTRL, 0xf, 0xf, true);
#endif
    return x + __builtin_bit_cast(float, r);
}

union AF { f16x2 p[4]; f16x8 v; };

__global__ __launch_bounds__(256, 2) void nsde_kernel(
    const float* __restrict__ S0p, const float* __restrict__ Kp,
    const float* __restrict__ Tp,  const float* __restrict__ rfp,
    const float* __restrict__ V0p, const float* __restrict__ rhop,
    const float* __restrict__ Z1,  const float* __restrict__ Z2r,
    const float* __restrict__ W1,  const float* __restrict__ B1,
    const float* __restrict__ W2,  const float* __restrict__ B2,
    const float* __restrict__ W3,  const float* __restrict__ B3,
    float* __restrict__ out)
{
    __shared__ f16x8 w2frag[32 * 64];   // [net*8 + t*2 + kt][lane], 32 KB
    __shared__ u32x4 w1h[128];          // packed f16x2 W1 coeffs, 2 KB
    __shared__ f32x4 nv_lds[2][64];     // [buf][element] = pre-tanh o per net, 2 KB
    __shared__ float2 svx[4][64];       // [wave][element] {S,V} — wave-private, 2 KB

    const int tid  = threadIdx.x;
    const int wave = tid >> 6;
    const int lane = tid & 63;
    const int q    = lane >> 4;
    const int mA   = lane & 15;
    const float rf = rfp[0];

    // ---------------- stage weights into LDS (R6-validated layout) ----------------
    if (tid < 128) {
        const int net = tid >> 5, kt = (tid >> 4) & 1, jj = (tid >> 2) & 3, qq = tid & 3;
        const int u0 = kt * 32 + qq * 8 + 2 * jj, u1 = u0 + 1;
        const float* w1g = W1 + net * 256;
        const float* b1g = B1 + net * 64;
        f16x2 wS = { (_Float16)w1g[0 * 64 + u0], (_Float16)w1g[0 * 64 + u1] };
        f16x2 wV = { (_Float16)w1g[1 * 64 + u0], (_Float16)w1g[1 * 64 + u1] };
        f16x2 wt = { (_Float16)w1g[3 * 64 + u0], (_Float16)w1g[3 * 64 + u1] };
        f16x2 cc = { (_Float16)fmaf(rf, w1g[2 * 64 + u0], b1g[u0]),
                     (_Float16)fmaf(rf, w1g[2 * 64 + u1], b1g[u1]) };
        u32x4 slot;
        slot[0] = __builtin_bit_cast(u32, wS);
        slot[1] = __builtin_bit_cast(u32, wV);
        slot[2] = __builtin_bit_cast(u32, wt);
        slot[3] = __builtin_bit_cast(u32, cc);
        w1h[tid] = slot;
    }
    #pragma unroll
    for (int f = 0; f < 8; ++f) {
        const int id    = f * 256 + tid;
        const int lane_ = id & 63;
        const int fi    = id >> 6;
        const int net   = fi >> 3, t = (fi >> 1) & 3, kt = fi & 1;
        const int n     = 16 * t + (lane_ & 15);
        const int k0    = kt * 32 + (lane_ >> 4) * 8;
        const float* w2g = W2 + net * 4096;
        f16x8 h;
        #pragma unroll
        for (int jjj = 0; jjj < 8; ++jjj)
            h[jjj] = (_Float16)w2g[(k0 + jjj) * 64 + n];
        w2frag[id] = h;
    }
    __syncthreads();

    // ---------------- hoist wave-resident weights ----------------
    f16x8 Bf[4][2];
    #pragma unroll
    for (int t = 0; t < 4; ++t)
        #pragma unroll
        for (int kt = 0; kt < 2; ++kt)
            Bf[t][kt] = w2frag[(wave * 8 + t * 2 + kt) * 64 + lane];

    f16x2 cw[2][4][4];
    #pragma unroll
    for (int kt = 0; kt < 2; ++kt)
        #pragma unroll
        for (int jj = 0; jj < 4; ++jj) {
            u32x4 v = w1h[((wave * 2 + kt) * 4 + jj) * 4 + q];
            cw[kt][jj][0] = __builtin_bit_cast(f16x2, v[0]);
            cw[kt][jj][1] = __builtin_bit_cast(f16x2, v[1]);
            cw[kt][jj][2] = __builtin_bit_cast(f16x2, v[2]);
            cw[kt][jj][3] = __builtin_bit_cast(f16x2, v[3]);
        }

    // bias splats as MFMA C operands (hoisted -> no per-tile movs) + w3 per lane
    f32x4 cinit[4], w3v;
    #pragma unroll
    for (int t = 0; t < 4; ++t) {
        const float b2s = B2[wave * 64 + 16 * t + mA];
        cinit[t][0] = b2s; cinit[t][1] = b2s; cinit[t][2] = b2s; cinit[t][3] = b2s;
        w3v[t] = W3[wave * 64 + 16 * t + mA];
    }
    const float b3n0 = B3[0], b3n1 = B3[1], b3n2 = B3[2], b3n3 = B3[3];

    // ---------------- per-element state ----------------
    const int ebase = blockIdx.x * 64;
    float dt_[4];
    #pragma unroll
    for (int mt = 0; mt < 4; ++mt)
        dt_[mt] = Tp[(ebase + mt * 16 + mA) & (D_OPT - 1)] * (1.0f / (float)M_STEPS);

    const int d_own = (ebase + lane) & (D_OPT - 1);
    const float dt_own  = Tp[d_own] * (1.0f / (float)M_STEPS);
    const float sdt_own = sqrtf(dt_own);

    // prime wave-private S,V exchange: lane owns element e == lane
    {
        float2 sv0; sv0.x = S0p[d_own]; sv0.y = V0p[0];
        svx[wave][lane] = sv0;
    }

    const float rho   = rhop[0];
    const float rho_c = sqrtf(1.0f - rho * rho);
    const size_t estep = (size_t)N_SIM * D_OPT;
    const float* z1p = Z1  + (size_t)ebase + (size_t)lane;
    const float* z2p = Z2r + (size_t)ebase + (size_t)lane;

    float Sfin = 0.0f;

    #pragma unroll 1
    for (int s = 0; s < M_STEPS; ++s) {
        // own-element z loads (issued early)
        const float z1  = *z1p;
        const float z2r = *z2p;
        z1p += estep; z2p += estep;

        // read S,V for this lane's 4 fragment elements (wave-private LDS,
        // ordered vs last step's write by same-wave DS ordering)
        float Smt[4], Vmt[4];
        #pragma unroll
        for (int mt = 0; mt < 4; ++mt) {
            float2 sv = svx[wave][mt * 16 + mA];
            Smt[mt] = sv.x; Vmt[mt] = sv.y;
        }
        float2 svo = svx[wave][lane];   // own element (pre-update value)

        #pragma unroll
        for (int mt = 0; mt < 4; ++mt) {
            const f16x2 S2 = pk2(Smt[mt]);
            const f16x2 V2 = pk2(Vmt[mt]);
            const f16x2 T2 = pk2(dt_[mt] * (float)s);

            // layer 1 (packed fp16) straight into A-fragments
            AF a0, a1;
            #pragma unroll
            for (int jj = 0; jj < 4; ++jj) {
                a0.p[jj] = pk_relu(PK_FMA(S2, cw[0][jj][0],
                              PK_FMA(V2, cw[0][jj][1],
                               PK_FMA(T2, cw[0][jj][2], cw[0][jj][3]))));
                a1.p[jj] = pk_relu(PK_FMA(S2, cw[1][jj][0],
                              PK_FMA(V2, cw[1][jj][1],
                               PK_FMA(T2, cw[1][jj][2], cw[1][jj][3]))));
            }

            // layer 2 (MFMA, C = bias splat) + fused layer-3 partial
            float op[4] = {0.f, 0.f, 0.f, 0.f};
            #pragma unroll
            for (int t = 0; t < 4; ++t) {
                f32x4 acc = __builtin_amdgcn_mfma_f32_16x16x32_f16(
                                a0.v, Bf[t][0], cinit[t], 0, 0, 0);
                acc = __builtin_amdgcn_mfma_f32_16x16x32_f16(
                                a1.v, Bf[t][1], acc, 0, 0, 0);
                #pragma unroll
                for (int r = 0; r < 4; ++r)
                    op[r] = fmaf(fmaxf(acc[r], 0.0f), w3v[t], op[r]);
            }

            // 16-lane rotation butterfly (fused DPP adds)
            #pragma unroll
            for (int r = 0; r < 4; ++r) {
                op[r] = ror_add<0x128>(op[r]);
                op[r] = ror_add<0x124>(op[r]);
                op[r] = ror_add<0x122>(op[r]);
                op[r] = ror_add<0x121>(op[r]);
            }

            // writers: lanes mA<4 store pre-tanh o for element mt*16+4q+mA
            if (mA < 4) {
                const float osel = (mA == 0) ? op[0] : (mA == 1) ? op[1]
                                 : (mA == 2) ? op[2] : op[3];
                ((float*)&nv_lds[s & 1][mt * 16 + 4 * q + mA])[wave] = osel;
            }
        }

        __syncthreads();

        // ---- once-per-lane SDE update of own element e == lane ----
        {
            const f32x4 o4 = nv_lds[s & 1][lane];
            const float e0 = __expf(2.0f * (o4[0] + b3n0));
            const float e1 = __expf(2.0f * (o4[1] + b3n1));
            const float e2 = __expf(2.0f * (o4[2] + b3n2));
            const float e3 = __expf(2.0f * (o4[3] + b3n3));
            const float N0 = 1.0f - 2.0f / (e0 + 1.0f);
            const float N1 = 1.0f - 2.0f / (e1 + 1.0f);
            const float N2 = 1.0f - 2.0f / (e2 + 1.0f);
            const float N3 = 1.0f - 2.0f / (e3 + 1.0f);
            const float z2 = fmaf(rho, z1, rho_c * z2r);
            const float fS = fmaf(N1 * sdt_own, z1, N0 * dt_own);
            const float fV = fmaf(N3 * sdt_own, z2, N2 * dt_own);
            const float Sn = fmaf(svo.x, fS, svo.x);
            const float Vn = fmaf(svo.y, fV, svo.y);
            float2 svn; svn.x = Sn; svn.y = Vn;
            svx[wave][lane] = svn;
            Sfin = Sn;
        }
    }

    // ---- payoff: wave 0, lane == element (once per element by construction) ----
    if (wave == 0) {
        const float Td  = dt_own * (float)M_STEPS;
        const float pay = fmaxf(Sfin - Kp[d_own], 0.0f);
        atomicAdd(&out[d_own], __expf(-rf * Td) * pay * (1.0f / (float)N_SIM));
    }
}

extern "C" void kernel_launch(void* const* d_in, const int* in_sizes, int n_in,
                              void* d_out, int out_size, void* d_ws, size_t ws_size,
                              hipStream_t stream)
{
    const float* S0  = (const float*)d_in[0];
    const float* K   = (const float*)d_in[1];
    const float* T   = (const float*)d_in[2];
    const float* rf  = (const float*)d_in[3];
    const float* V0  = (const float*)d_in[4];
    const float* rho = (const float*)d_in[5];
    const float* Z1  = (const float*)d_in[6];
    const float* Z2r = (const float*)d_in[7];
    const float* W1  = (const float*)d_in[8];
    const float* B1  = (const float*)d_in[9];
    const float* W2  = (const float*)d_in[10];
    const float* B2  = (const float*)d_in[11];
    const float* W3  = (const float*)d_in[12];
    const float* B3  = (const float*)d_in[13];
    float* out = (float*)d_out;

    hipMemsetAsync(out, 0, (size_t)out_size * sizeof(float), stream);

    const int total = N_SIM * D_OPT;              // 262144 elements
    const int grid  = total / 64;                 // 64 elements per block
    nsde_kernel<<<grid, 256, 0, stream>>>(S0, K, T, rf, V0, rho, Z1, Z2r,
                                          W1, B1, W2, B2, W3, B3, out);
}